// Round 1
// 674.608 us; speedup vs baseline: 1.0047x; 1.0047x over previous
//
#include <hip/hip_runtime.h>

// HDC token encoder: out[b,i,d] = item_memory[token_ids[b,i]][(d - i) mod D] * 0.01f
// B=8, S=2048, V=256, D=10000. Every +/-1 row has L2 norm exactly 100, so the
// normalize is a constant scale by 0.01f (bit-exact vs reference, verified R0).
//
// Structure (R5-best, ~145 us kernel) + R9 token-sorted XCD scheduling:
// - two-phase per thread: all 10 independent gather loads -> one vmcnt wait ->
//   10-store burst, so no load-wait ever drains a store from the shared vmcnt
//   FIFO (R5 vs R4: -4 us).
// - NONTEMPORAL stores: bypass L2 so the 655 MB write stream doesn't thrash
//   the L2-resident item_memory reads (R8 A/B: plain stores +29 us).
// - unaligned (4B-aligned) global_load_dwordx4 gathers: source phase (s mod 4)
//   is row-uniform; only the one row-end-crossing chunk takes the scalar path.
// - R9: counting-sort row indices by token (prep kernel, V=256 bins), then map
//   sorted position p = (bid%8)*2048 + bid/8 so each XCD (bid%8 round-robin,
//   measured) works a contiguous token range: per-XCD read working set drops
//   from 10.24 MB (>> 4 MB L2, ~60% miss -> ~400 MB L3 reads crossing the
//   XCD<->IOD fabric alongside the 655 MB store stream) to ~1.3 MB (L2-hit).
//   Store structure is unchanged: one block per output row, contiguous burst.

#define B_ 8
#define S_ 2048
#define V_ 256
#define D_ 10000
#define NROWS (B_ * S_)                  // 16384
#define NCH 10                           // ceil(2500 chunks / 256 threads)

typedef float vf4  __attribute__((ext_vector_type(4)));              // 16B aligned
typedef float vf4u __attribute__((ext_vector_type(4), aligned(4)));  // 4B aligned

// Row indices sorted by token, rebuilt every launch (module-scope: no d_ws dependence).
__device__ int g_sorted[NROWS];

// Counting sort of the 16384 (b,i) rows by token id. Single block; all
// __syncthreads are block-uniform. Intra-bucket order is nondeterministic
// (LDS atomicAdd) but every row is scattered exactly once and the main kernel
// writes each output row exactly once, so results are order-independent.
__global__ __launch_bounds__(1024) void hdc_sort_rows(const int* __restrict__ token_ids)
{
    __shared__ int counts[V_];
    __shared__ int offsets[V_];
    const int tid = threadIdx.x;

    if (tid < V_) counts[tid] = 0;
    __syncthreads();

    for (int r = tid; r < NROWS; r += 1024)
        atomicAdd(&counts[token_ids[r]], 1);
    __syncthreads();

    // inclusive Hillis-Steele scan over 256 bins (threads >= 256 just sync)
    if (tid < V_) offsets[tid] = counts[tid];
    __syncthreads();
    for (int d = 1; d < V_; d <<= 1) {
        int v = 0;
        if (tid < V_ && tid >= d) v = offsets[tid - d];
        __syncthreads();
        if (tid < V_ && tid >= d) offsets[tid] += v;
        __syncthreads();
    }
    // inclusive -> exclusive
    int excl = 0;
    if (tid < V_ && tid > 0) excl = offsets[tid - 1];
    __syncthreads();
    if (tid < V_) offsets[tid] = excl;
    __syncthreads();

    for (int r = tid; r < NROWS; r += 1024) {
        int t = token_ids[r];
        int pos = atomicAdd(&offsets[t], 1);
        g_sorted[pos] = r;
    }
}

__global__ __launch_bounds__(256) void hdc_encode(
    const int* __restrict__ token_ids,
    const float* __restrict__ item_memory,
    float* __restrict__ out)
{
    // XCD-clustered schedule: XCD x = bid%8 (measured round-robin) handles
    // sorted positions [x*2048, (x+1)*2048) in ascending token order.
    const int bid = blockIdx.x;
    const int p   = (bid & 7) * (NROWS / 8) + (bid >> 3);
    const int row = g_sorted[p];         // block-uniform

    const int i   = row & (S_ - 1);      // shift amount (S is a power of two)
    const int tok = token_ids[row];      // block-uniform -> scalar load

    const float* __restrict__ src = item_memory + (size_t)tok * D_;
    float*       __restrict__ dst = out + (size_t)row * D_;

    const int tid = threadIdx.x;
    // chunks c = tid + 256*j, j in [0, nj); 2500 = 9*256 + 196
    const int nj = (tid < 2500 - 9 * 256) ? NCH : NCH - 1;

    // Phase 1: gather all chunks into registers. s_j = (4*tid - i + 1024*j) mod D.
    // Per thread at most ONE chunk crosses the row end (min circular gap of the
    // 10 offsets is 784 > 3), so the scalar wrap path runs once at most.
    vf4 v[NCH];
    int s = 4 * tid - i;
    if (s < 0) s += D_;
    #pragma unroll
    for (int j = 0; j < NCH; ++j) {
        if (j < nj) {
            if (s <= D_ - 4) {
                v[j] = *reinterpret_cast<const vf4u*>(src + s);  // 4B-aligned dwordx4
            } else {
                int s1 = s + 1; if (s1 >= D_) s1 -= D_;
                int s2 = s + 2; if (s2 >= D_) s2 -= D_;
                int s3 = s + 3; if (s3 >= D_) s3 -= D_;
                v[j].x = src[s]; v[j].y = src[s1]; v[j].z = src[s2]; v[j].w = src[s3];
            }
        }
        s += 1024;                        // 4 * 256
        if (s >= D_) s -= D_;
    }

    // Phase 2: fire-and-forget nontemporal store burst (contiguous 1KB per
    // wave-instruction; never waited on).
    vf4* __restrict__ dst4 = reinterpret_cast<vf4*>(dst);
    #pragma unroll
    for (int j = 0; j < NCH; ++j) {
        if (j < nj) {
            __builtin_nontemporal_store(v[j] * 0.01f, dst4 + tid + 256 * j);
        }
    }
}

extern "C" void kernel_launch(void* const* d_in, const int* in_sizes, int n_in,
                              void* d_out, int out_size, void* d_ws, size_t ws_size,
                              hipStream_t stream)
{
    const int*   token_ids   = (const int*)d_in[0];
    const float* item_memory = (const float*)d_in[1];
    float*       out         = (float*)d_out;

    hdc_sort_rows<<<dim3(1), dim3(1024), 0, stream>>>(token_ids);
    hdc_encode<<<dim3(B_ * S_), dim3(256), 0, stream>>>(token_ids, item_memory, out);
}